// Round 2
// baseline (1095.893 us; speedup 1.0000x reference)
//
#include <hip/hip_runtime.h>
#include <hip/hip_bf16.h>

// VQ: x [N=131072, D=64] fp32, E [D=64, K=1024] fp32.
// codes[n] = argmin_k ( e_sq[k] - 2 x_n.e_k )   (y_sq is a per-row constant -> dropped;
//                                                 argmin computed in FP64 so ordering is
//                                                 exact vs the harness's numpy-f64 ref)
// out[n][d] = E[d][codes[n]]
//
// R1 failed with absmax 0.305: ~few rows flipped argmin due to fp32 rounding-order
// mismatch vs the reference. Fix: fp64 accumulation (products of fp32 are exact in
// fp64; 64-term f64 sum error ~1e-15 << typical min-gap 0.65).

constexpr int D = 64;
constexpr int K = 1024;
constexpr int KG = 16;   // accumulators per thread (doubles -> 32 VGPRs)

// ---- prep: e_sq64[k] = sum_d E[d][k]^2 (f64); Ed[d][k] = (double)E[d][k];
//            ET[k][d] = E[d][k] (fp32, for the contiguous epilogue gather) ----
__global__ __launch_bounds__(256) void vq_prep(const float* __restrict__ E,
                                               double* __restrict__ e_sq64,
                                               double* __restrict__ Ed,
                                               float* __restrict__ ET) {
    int k = blockIdx.x * blockDim.x + threadIdx.x;   // 0..K-1
    if (k >= K) return;
    double s = 0.0;
    #pragma unroll
    for (int d = 0; d < D; ++d) {
        float v = E[d * K + k];          // coalesced across k
        double vd = (double)v;
        s = fma(vd, vd, s);
        Ed[d * K + k] = vd;
        ET[k * D + d] = v;
    }
    e_sq64[k] = s;
}

// ---- main: fp64 distances + argmin + fp32 gather ----
__global__ __launch_bounds__(256) void vq_main(const float* __restrict__ x,
                                               const double* __restrict__ Ed,
                                               const double* __restrict__ e_sq64,
                                               const float* __restrict__ ET,
                                               float* __restrict__ out,
                                               int N) {
    int row = blockIdx.x * 256 + threadIdx.x;
    if (row >= N) return;

    // x row -> 64 VGPRs (fp32; converted to f64 per use — conversion is exact)
    float xr[D];
    const float4* xp = (const float4*)(x + (size_t)row * D);
    #pragma unroll
    for (int i = 0; i < D / 4; ++i) {
        float4 v = xp[i];
        xr[4 * i + 0] = v.x;
        xr[4 * i + 1] = v.y;
        xr[4 * i + 2] = v.z;
        xr[4 * i + 3] = v.w;
    }

    double best = 1.0e300;
    int bestk = 0;

    for (int k0 = 0; k0 < K; k0 += KG) {
        double acc[KG];
        #pragma unroll
        for (int j = 0; j < KG; ++j) acc[j] = 0.0;

        // Ed indices are wave-uniform -> s_load (SMEM pipe); hot loop = v_fma_f64
        #pragma unroll
        for (int d = 0; d < D; ++d) {
            const double* Er = Ed + d * K + k0;
            double xd = (double)xr[d];       // one v_cvt per (d,k0): 6% of FMA count
            #pragma unroll
            for (int j = 0; j < KG; ++j)
                acc[j] = fma(xd, Er[j], acc[j]);
        }

        #pragma unroll
        for (int j = 0; j < KG; ++j) {
            double s = fma(-2.0, acc[j], e_sq64[k0 + j]);
            if (s < best) { best = s; bestk = k0 + j; }  // strict < : first index wins
        }
    }

    // gather: contiguous 256B per thread from transposed fp32 codebook (exact copy)
    float4* op = (float4*)(out + (size_t)row * D);
    const float4* ep = (const float4*)(ET + (size_t)bestk * D);
    #pragma unroll
    for (int i = 0; i < D / 4; ++i) op[i] = ep[i];
}

extern "C" void kernel_launch(void* const* d_in, const int* in_sizes, int n_in,
                              void* d_out, int out_size, void* d_ws, size_t ws_size,
                              hipStream_t stream) {
    const float* x = (const float*)d_in[0];
    const float* E = (const float*)d_in[1];
    float* out = (float*)d_out;

    int N = in_sizes[0] / D;   // 131072

    // workspace layout (all 16B-aligned):
    //   e_sq64 : K doubles        (8 KB)
    //   Ed     : D*K doubles      (512 KB)
    //   ET     : K*D floats       (256 KB)
    double* e_sq64 = (double*)d_ws;
    double* Ed     = e_sq64 + K;
    float*  ET     = (float*)(Ed + (size_t)D * K);

    vq_prep<<<(K + 255) / 256, 256, 0, stream>>>(E, e_sq64, Ed, ET);
    vq_main<<<(N + 255) / 256, 256, 0, stream>>>(x, Ed, e_sq64, ET, out, N);
}

// Round 3
// 366.865 us; speedup vs baseline: 2.9872x; 2.9872x over previous
//
#include <hip/hip_runtime.h>
#include <hip/hip_bf16.h>
#include <stdint.h>

// VQ: x [N=131072, D=64] fp32, E [D=64, K=1024] fp32.
// Architecture: fp32 screen (argmin + top2-gap) at vector-FMA rate; rows whose
// fp32 gap < TAU get exact fp64 re-argmin in a sparse refine pass (R2 proved
// f64 ordering matches the harness np ref bit-for-bit; screen fp32 error
// bound ~1.6e-5 << TAU=1e-3 => no unflagged row can be wrong).
//
// R2 failure mode fixed here: 1-thread-per-row gave 8 waves/CU + SMEM-serialized
// E reads (VALUBusy 24%). Now: thread owns 4 codes (E loads coalesced vector),
// block owns 32 rows (x broadcast from LDS), 128 FMAs per 16B E load.

typedef unsigned long long u64;

constexpr int D   = 64;
constexpr int K   = 1024;
constexpr int K4  = K / 4;
constexpr int R   = 32;    // rows per screen block
constexpr int KPT = 4;     // codes per thread (256 threads * 4 = K)
constexpr int XPAD = 36;   // padded fp32 stride for xT[d][*] (144B, 16B-aligned)
constexpr float TAU = 1e-3f;

// monotone fp32 -> u32 map (min on map == min on float); finite inputs only
__device__ __forceinline__ uint32_t fmap(float v) {
    uint32_t u = __float_as_uint(v);
    return (u & 0x80000000u) ? ~u : (u | 0x80000000u);
}
__device__ __forceinline__ float funmap(uint32_t m) {
    uint32_t u = (m & 0x80000000u) ? (m ^ 0x80000000u) : ~m;
    return __uint_as_float(u);
}
// merge two sorted top-2 pairs (b<=s); keys = (mapped_val<<32)|k, all distinct
__device__ __forceinline__ void top2_merge(u64& b, u64& s, u64 ob, u64 os) {
    if (ob < b) { s = (b < os) ? b : os; b = ob; }
    else        { s = (ob < s) ? ob : s; }
}
__device__ __forceinline__ u64 shfl_xor_u64(u64 v, int m) {
    uint32_t lo = (uint32_t)v, hi = (uint32_t)(v >> 32);
    lo = (uint32_t)__shfl_xor((int)lo, m, 64);
    hi = (uint32_t)__shfl_xor((int)hi, m, 64);
    return ((u64)hi << 32) | lo;
}
__device__ __forceinline__ double shfl_xor_f64(double v, int m) {
    int lo = __double2loint(v), hi = __double2hiint(v);
    lo = __shfl_xor(lo, m, 64);
    hi = __shfl_xor(hi, m, 64);
    return __hiloint2double(hi, lo);
}

// ---- prep: e_sq (f64 + f32 view), ET[k][d] transposed codebook, count=0 ----
__global__ __launch_bounds__(256) void vq_prep(const float* __restrict__ E,
                                               double* __restrict__ e_sq64,
                                               float* __restrict__ e_sq32,
                                               float* __restrict__ ET,
                                               int* __restrict__ count) {
    int k = blockIdx.x * 256 + threadIdx.x;
    if (k == 0) *count = 0;
    if (k >= K) return;
    double s = 0.0;
    for (int d = 0; d < D; ++d) {
        float v = E[d * K + k];          // coalesced across k
        s = fma((double)v, (double)v, s);
        ET[k * D + d] = v;
    }
    e_sq64[k] = s;
    e_sq32[k] = (float)s;
}

// ---- screen: fp32 distances, per-row top2 over all K, gather, flag ----
__global__ __launch_bounds__(256, 3) void vq_screen(
    const float* __restrict__ x, const float* __restrict__ E,
    const float* __restrict__ e_sq32, const float* __restrict__ ET,
    float* __restrict__ out, int* __restrict__ count, int* __restrict__ list) {
    __shared__ float xT[D * XPAD];         // 9.2 KB, x transposed [d][r]
    __shared__ u64 KB[8 * 256];            // 16 KB
    __shared__ u64 KS[8 * 256];            // 16 KB
    __shared__ int bk[R];

    const int t = threadIdx.x;
    const int rowbase = blockIdx.x * R;

    // stage 32 rows of x, transposed (one-time; write conflicts negligible)
    {
        int r = t >> 3, d0 = (t & 7) * 8;
        const float4* xp = (const float4*)(x + (size_t)(rowbase + r) * D + d0);
        float4 a = xp[0], b = xp[1];
        float v[8] = {a.x, a.y, a.z, a.w, b.x, b.y, b.z, b.w};
        #pragma unroll
        for (int i = 0; i < 8; ++i) xT[(d0 + i) * XPAD + r] = v[i];
    }
    __syncthreads();

    float acc[R][KPT];   // 128 VGPRs: acc[r][j] = dot(x_row_r, E_col_{4t+j})
    #pragma unroll
    for (int r = 0; r < R; ++r)
        #pragma unroll
        for (int j = 0; j < KPT; ++j) acc[r][j] = 0.f;

    const float4* ecol = (const float4*)E + t;   // E[d][4t..4t+4) at [d*K4 + t]
    for (int d0 = 0; d0 < D; d0 += 4) {
        float4 e0 = ecol[(d0 + 0) * K4];
        float4 e1 = ecol[(d0 + 1) * K4];
        float4 e2 = ecol[(d0 + 2) * K4];
        float4 e3 = ecol[(d0 + 3) * K4];
        #pragma unroll
        for (int i = 0; i < 4; ++i) {
            float4 e = (i == 0) ? e0 : (i == 1) ? e1 : (i == 2) ? e2 : e3;
            const float* xrow = &xT[(d0 + i) * XPAD];
            #pragma unroll
            for (int rc = 0; rc < 4; ++rc) {
                const float4* xv = (const float4*)(xrow + rc * 8);
                float4 xa = xv[0], xb = xv[1];                 // uniform -> LDS broadcast
                float xs[8] = {xa.x, xa.y, xa.z, xa.w, xb.x, xb.y, xb.z, xb.w};
                #pragma unroll
                for (int q = 0; q < 8; ++q) {
                    int r = rc * 8 + q;
                    acc[r][0] = fmaf(xs[q], e.x, acc[r][0]);
                    acc[r][1] = fmaf(xs[q], e.y, acc[r][1]);
                    acc[r][2] = fmaf(xs[q], e.z, acc[r][2]);
                    acc[r][3] = fmaf(xs[q], e.w, acc[r][3]);
                }
            }
        }
    }

    const float4 es = ((const float4*)e_sq32)[t];
    const int myk0 = t * KPT;

    #pragma unroll 4
    for (int g = 0; g < 4; ++g) {                 // row groups of 8
        __syncthreads();                           // KB/KS reuse barrier
        #pragma unroll
        for (int q = 0; q < 8; ++q) {
            int r = g * 8 + q;
            float v0 = fmaf(-2.f, acc[r][0], es.x);
            float v1 = fmaf(-2.f, acc[r][1], es.y);
            float v2 = fmaf(-2.f, acc[r][2], es.z);
            float v3 = fmaf(-2.f, acc[r][3], es.w);
            u64 k0 = ((u64)fmap(v0) << 32) | (uint32_t)(myk0 + 0);
            u64 k1 = ((u64)fmap(v1) << 32) | (uint32_t)(myk0 + 1);
            u64 k2 = ((u64)fmap(v2) << 32) | (uint32_t)(myk0 + 2);
            u64 k3 = ((u64)fmap(v3) << 32) | (uint32_t)(myk0 + 3);
            u64 b01 = min(k0, k1), s01 = max(k0, k1);
            u64 b23 = min(k2, k3), s23 = max(k2, k3);
            u64 b, s;
            if (b01 <= b23) { b = b01; s = min(s01, b23); }
            else            { b = b23; s = min(s23, b01); }
            KB[q * 256 + t] = b;
            KS[q * 256 + t] = s;
        }
        __syncthreads();
        // 32 threads per row reduce 256 top2 pairs
        int rr = t >> 5, j = t & 31;
        u64 b = KB[rr * 256 + j], s = KS[rr * 256 + j];
        #pragma unroll
        for (int p = 1; p < 8; ++p)
            top2_merge(b, s, KB[rr * 256 + j + p * 32], KS[rr * 256 + j + p * 32]);
        #pragma unroll
        for (int m = 16; m >= 1; m >>= 1) {
            u64 ob = shfl_xor_u64(b, m);
            u64 os = shfl_xor_u64(s, m);
            top2_merge(b, s, ob, os);
        }
        if (j == 0) {
            int r = g * 8 + rr;
            bk[r] = (int)(uint32_t)(b & 0xFFFFFFFFu);
            float vb = funmap((uint32_t)(b >> 32));
            float vs = funmap((uint32_t)(s >> 32));
            if (vs - vb < TAU) {                     // ambiguous under fp32 -> refine
                int idx = atomicAdd(count, 1);
                list[idx] = rowbase + r;
            }
        }
    }
    __syncthreads();

    // gather: thread t writes 8 floats of row (t>>3)
    {
        int r = t >> 3, c = (t & 7) * 8;
        const float4* ep = (const float4*)(ET + (size_t)bk[r] * D + c);
        float4* op = (float4*)(out + (size_t)(rowbase + r) * D + c);
        op[0] = ep[0];
        op[1] = ep[1];
    }
}

// ---- refine: exact fp64 argmin for flagged rows (expected ~200 rows) ----
__global__ __launch_bounds__(256) void vq_refine(
    const float* __restrict__ x, const float* __restrict__ E,
    const double* __restrict__ e_sq64, const float* __restrict__ ET,
    float* __restrict__ out, const int* __restrict__ count,
    const int* __restrict__ list) {
    __shared__ double xs[D];
    __shared__ double wbv[4];
    __shared__ int wbk[4];
    __shared__ int bks;
    const int t = threadIdx.x;
    const int n = *count;
    for (int i = blockIdx.x; i < n; i += gridDim.x) {
        int row = list[i];
        if (t < D) xs[t] = (double)x[(size_t)row * D + t];
        __syncthreads();
        double best = 1.0e300; int bestk = 0;
        #pragma unroll
        for (int j = 0; j < KPT; ++j) {
            int k = t * KPT + j;
            double a = 0.0;
            for (int d = 0; d < D; ++d)
                a = fma(xs[d], (double)E[d * K + k], a);
            double v = fma(-2.0, a, e_sq64[k]);
            if (v < best) { best = v; bestk = k; }
        }
        #pragma unroll
        for (int m = 32; m >= 1; m >>= 1) {
            double ov = shfl_xor_f64(best, m);
            int    ok = __shfl_xor(bestk, m, 64);
            if (ov < best || (ov == best && ok < bestk)) { best = ov; bestk = ok; }
        }
        if ((t & 63) == 0) { wbv[t >> 6] = best; wbk[t >> 6] = bestk; }
        __syncthreads();
        if (t == 0) {
            double bv = wbv[0]; int bb = wbk[0];
            for (int w = 1; w < 4; ++w)
                if (wbv[w] < bv || (wbv[w] == bv && wbk[w] < bb)) { bv = wbv[w]; bb = wbk[w]; }
            bks = bb;
        }
        __syncthreads();
        if (t < D) out[(size_t)row * D + t] = ET[(size_t)bks * D + t];
        __syncthreads();   // xs reuse
    }
}

extern "C" void kernel_launch(void* const* d_in, const int* in_sizes, int n_in,
                              void* d_out, int out_size, void* d_ws, size_t ws_size,
                              hipStream_t stream) {
    const float* x = (const float*)d_in[0];
    const float* E = (const float*)d_in[1];
    float* out = (float*)d_out;
    int N = in_sizes[0] / D;   // 131072

    // ws layout: e_sq64 8KB | e_sq32 4KB | ET 256KB | count 16B | list N*4B
    char* w = (char*)d_ws;
    double* e_sq64 = (double*)w;                     w += K * sizeof(double);
    float*  e_sq32 = (float*)w;                      w += K * sizeof(float);
    float*  ET     = (float*)w;                      w += (size_t)K * D * sizeof(float);
    int*    count  = (int*)w;                        w += 16;
    int*    list   = (int*)w;

    vq_prep<<<(K + 255) / 256, 256, 0, stream>>>(E, e_sq64, e_sq32, ET, count);
    vq_screen<<<N / R, 256, 0, stream>>>(x, E, e_sq32, ET, out, count, list);
    vq_refine<<<1024, 256, 0, stream>>>(x, E, e_sq64, ET, out, count, list);
}

// Round 5
// 215.227 us; speedup vs baseline: 5.0918x; 1.7045x over previous
//
#include <hip/hip_runtime.h>
#include <hip/hip_bf16.h>
#include <stdint.h>

// VQ: x [N=131072, D=64] fp32, E [D=64, K=1024] fp32.
// R5: bf16 MFMA screen (16x16x32, VERIFIED layouts only) with hi/lo split for
// ~1.5e-4 screen error; distances = e_sq - 2 x.e computed in the MFMA chain
// (C-init = e_sq, B tables hold -2E split into bf16 hi+lo). Rows with screen
// gap < TAU=1e-3 get exact fp64 re-argmin (R2/R3-proven refine kernel).
// Verified facts used: A[m=lane&15][k=(lane>>4)*8+j] (m89/m91/m120),
// C/D col=lane&15 row=(lane>>4)*4+reg (m89/m91), frag types short8/float4.

typedef unsigned long long u64;
typedef short short8 __attribute__((ext_vector_type(8)));
typedef float f32x4 __attribute__((ext_vector_type(4)));

constexpr int D = 64;
constexpr int K = 1024;
constexpr int XS = 72;           // LDS row stride in bf16 elems (144 B, 16B-aligned frags)
constexpr int LCAP = 32768;      // refine-list capacity (cap, never near-reached)
constexpr float TAU = 1e-3f;

__device__ __forceinline__ unsigned short bf16_rne(float v) {
    uint32_t u = __float_as_uint(v);
    uint32_t r = u + 0x7FFFu + ((u >> 16) & 1u);
    return (unsigned short)(r >> 16);
}
__device__ __forceinline__ float bf16_f(unsigned short h) {
    return __uint_as_float(((uint32_t)h) << 16);
}
// monotone fp32 -> u32 map (min preserved) — R3-proven
__device__ __forceinline__ uint32_t fmap(float v) {
    uint32_t u = __float_as_uint(v);
    return (u & 0x80000000u) ? ~u : (u | 0x80000000u);
}
__device__ __forceinline__ float funmap(uint32_t m) {
    uint32_t u = (m & 0x80000000u) ? (m ^ 0x80000000u) : ~m;
    return __uint_as_float(u);
}
__device__ __forceinline__ void top2_merge(u64& b, u64& s, u64 ob, u64 os) {
    if (ob < b) { s = (b < os) ? b : os; b = ob; }
    else        { s = (ob < s) ? ob : s; }
}
__device__ __forceinline__ u64 shfl_xor_u64(u64 v, int m) {
    uint32_t lo = (uint32_t)v, hi = (uint32_t)(v >> 32);
    lo = (uint32_t)__shfl_xor((int)lo, m, 64);
    hi = (uint32_t)__shfl_xor((int)hi, m, 64);
    return ((u64)hi << 32) | lo;
}
__device__ __forceinline__ double shfl_xor_f64(double v, int m) {
    int lo = __double2loint(v), hi = __double2hiint(v);
    lo = __shfl_xor(lo, m, 64);
    hi = __shfl_xor(hi, m, 64);
    return __hiloint2double(hi, lo);
}

// ---- prep: e_sq (f64/f32), ET[k][d] gather table, Bhi/Blo fragment-linear
//      bf16 tables of -2E (hi + residual lo). grid 256 x 256. ----
__global__ __launch_bounds__(256) void vq_prep(const float* __restrict__ E,
                                               double* __restrict__ e_sq64,
                                               float* __restrict__ e_sq32,
                                               float* __restrict__ ET,
                                               unsigned short* __restrict__ Bhi,
                                               unsigned short* __restrict__ Blo,
                                               int* __restrict__ count) {
    int tid = blockIdx.x * 256 + threadIdx.x;        // 0..65535
    if (tid == 0) *count = 0;
    if (tid < K) {
        int k = tid;
        double s = 0.0;
        for (int d = 0; d < D; ++d) {
            float v = E[d * K + k];
            s = fma((double)v, (double)v, s);
            ET[k * D + d] = v;
        }
        e_sq64[k] = s;
        e_sq32[k] = (float)s;
    }
    // table entry: frag f = t*2+c (t=tile 0..63, c=k-chunk 0..1), lane l, slot j
    //   value = -2*E[d][code], d = 32c + 8*(l>>4) + j, code = 16t + (l&15)
    {
        int j = tid & 7;
        int l = (tid >> 3) & 63;
        int f = tid >> 9;            // 0..127
        int c = f & 1;
        int t = f >> 1;
        int d = 32 * c + 8 * (l >> 4) + j;
        int code = 16 * t + (l & 15);
        float v = -2.0f * E[d * K + code];
        unsigned short h = bf16_rne(v);
        Bhi[tid] = h;
        Blo[tid] = bf16_rne(v - bf16_f(h));
    }
}

// ---- screen: block = 64 rows (4 waves x 16), all 1024 codes ----
__global__ __launch_bounds__(256, 3) void vq_screen(
    const float* __restrict__ x,
    const short8* __restrict__ Bh, const short8* __restrict__ Bl,
    const float* __restrict__ e_sq32, const float* __restrict__ ET,
    float* __restrict__ out, int* __restrict__ count, int* __restrict__ list) {
    __shared__ unsigned short xhi[64 * XS];   // 9.2 KB
    __shared__ unsigned short xlo[64 * XS];   // 9.2 KB
    __shared__ float esq[K];                  // 4 KB
    __shared__ int bk[64];

    const int t0 = threadIdx.x;
    const int base = blockIdx.x * 64;

    // stage e_sq
    #pragma unroll
    for (int i = 0; i < 4; ++i) esq[i * 256 + t0] = e_sq32[i * 256 + t0];

    // stage x, split into bf16 hi + lo (thread owns 16 floats of one row)
    {
        int row = t0 >> 2, seg = t0 & 3;
        const float4* xp = (const float4*)(x + (size_t)(base + row) * D + seg * 16);
        short8 H0, H1, L0, L1;
        #pragma unroll
        for (int q = 0; q < 4; ++q) {
            float4 v = xp[q];
            float vv[4] = {v.x, v.y, v.z, v.w};
            #pragma unroll
            for (int e = 0; e < 4; ++e) {
                unsigned short h = bf16_rne(vv[e]);
                unsigned short lo = bf16_rne(vv[e] - bf16_f(h));
                int p = q * 4 + e;
                if (p < 8) { H0[p] = (short)h; L0[p] = (short)lo; }
                else       { H1[p - 8] = (short)h; L1[p - 8] = (short)lo; }
            }
        }
        int off = row * XS + seg * 16;
        *(short8*)&xhi[off] = H0;  *(short8*)&xhi[off + 8] = H1;
        *(short8*)&xlo[off] = L0;  *(short8*)&xlo[off + 8] = L1;
    }
    __syncthreads();

    const int wid = t0 >> 6, l = t0 & 63;
    const int col = l & 15, quad = l >> 4;

    // A fragments (verified layout: m = lane&15, k = quad*8 + j, chunks k0=0/32)
    const int arow = wid * 16 + col;
    short8 Ah0 = *(const short8*)&xhi[arow * XS + quad * 8];
    short8 Ah1 = *(const short8*)&xhi[arow * XS + 32 + quad * 8];
    short8 Al0 = *(const short8*)&xlo[arow * XS + quad * 8];
    short8 Al1 = *(const short8*)&xlo[arow * XS + 32 + quad * 8];

    float best[4], sec[4];
    int bidx[4];
    #pragma unroll
    for (int r = 0; r < 4; ++r) { best[r] = 3.4e38f; sec[r] = 3.4e38f; bidx[r] = 0; }

    short8 bh0 = Bh[l], bh1 = Bh[64 + l];
    short8 bl0 = Bl[l], bl1 = Bl[64 + l];

    for (int t = 0; t < 64; ++t) {
        // prefetch next tile's B frags (t=63 wraps to 0 — valid memory, unused values)
        int fb = ((t + 1) & 63) * 128 + l;
        short8 nh0 = Bh[fb], nh1 = Bh[fb + 64];
        short8 nl0 = Bl[fb], nl1 = Bl[fb + 64];

        float esv = esq[t * 16 + col];             // same addr across quads -> broadcast
        f32x4 C1 = {esv, esv, esv, esv};
        f32x4 C2 = {0.f, 0.f, 0.f, 0.f};
        f32x4 C3 = {0.f, 0.f, 0.f, 0.f};
        C1 = __builtin_amdgcn_mfma_f32_16x16x32_bf16(Ah0, bh0, C1, 0, 0, 0);
        C1 = __builtin_amdgcn_mfma_f32_16x16x32_bf16(Ah1, bh1, C1, 0, 0, 0);
        C2 = __builtin_amdgcn_mfma_f32_16x16x32_bf16(Ah0, bl0, C2, 0, 0, 0);
        C2 = __builtin_amdgcn_mfma_f32_16x16x32_bf16(Ah1, bl1, C2, 0, 0, 0);
        C3 = __builtin_amdgcn_mfma_f32_16x16x32_bf16(Al0, bh0, C3, 0, 0, 0);
        C3 = __builtin_amdgcn_mfma_f32_16x16x32_bf16(Al1, bh1, C3, 0, 0, 0);

        int tc = t * 16;
        #pragma unroll
        for (int r = 0; r < 4; ++r) {
            float v = C1[r] + C2[r] + C3[r];
            bool lt = v < best[r];
            float mx = fmaxf(v, best[r]);
            best[r] = fminf(v, best[r]);
            sec[r]  = fminf(sec[r], mx);
            bidx[r] = lt ? tc : bidx[r];
        }
        bh0 = nh0; bh1 = nh1; bl0 = nl0; bl1 = nl1;
    }

    // per-register reduce across the 16 col-lanes (masks 1..8 preserve quad)
    #pragma unroll
    for (int r = 0; r < 4; ++r) {
        u64 b = ((u64)fmap(best[r]) << 32) | (uint32_t)(bidx[r] + col);
        u64 s = ((u64)fmap(sec[r]) << 32) | 0xFFFFFFFFu;
        #pragma unroll
        for (int m = 8; m >= 1; m >>= 1) {
            u64 ob = shfl_xor_u64(b, m);
            u64 os = shfl_xor_u64(s, m);
            top2_merge(b, s, ob, os);
        }
        if (col == 0) {
            int rowL = wid * 16 + quad * 4 + r;       // verified C row map
            bk[rowL] = (int)(uint32_t)(b & 0xFFFFFFFFu);
            float vb = funmap((uint32_t)(b >> 32));
            float vs = funmap((uint32_t)(s >> 32));
            if (vs - vb < TAU) {
                int idx = atomicAdd(count, 1);
                if (idx < LCAP) list[idx] = base + rowL;
            }
        }
    }
    __syncthreads();

    // gather: thread t0 copies 64 B of its row from ET
    {
        int row = t0 >> 2, seg = t0 & 3;
        const float4* ep = (const float4*)(ET + (size_t)bk[row] * D + seg * 16);
        float4* op = (float4*)(out + (size_t)(base + row) * D + seg * 16);
        op[0] = ep[0]; op[1] = ep[1]; op[2] = ep[2]; op[3] = ep[3];
    }
}

// ---- refine: exact fp64 argmin for flagged rows (R2/R3-proven) ----
__global__ __launch_bounds__(256) void vq_refine(
    const float* __restrict__ x, const float* __restrict__ E,
    const double* __restrict__ e_sq64, const float* __restrict__ ET,
    float* __restrict__ out, const int* __restrict__ count,
    const int* __restrict__ list) {
    __shared__ double xs[D];
    __shared__ double wbv[4];
    __shared__ int wbk[4];
    __shared__ int bks;
    const int t = threadIdx.x;
    int n = *count;
    if (n > LCAP) n = LCAP;
    for (int i = blockIdx.x; i < n; i += gridDim.x) {
        int row = list[i];
        if (t < D) xs[t] = (double)x[(size_t)row * D + t];
        __syncthreads();
        double best = 1.0e300; int bestk = 0;
        #pragma unroll
        for (int j = 0; j < 4; ++j) {
            int k = t * 4 + j;
            double a = 0.0;
            for (int d = 0; d < D; ++d)
                a = fma(xs[d], (double)E[d * K + k], a);
            double v = fma(-2.0, a, e_sq64[k]);
            if (v < best) { best = v; bestk = k; }
        }
        #pragma unroll
        for (int m = 32; m >= 1; m >>= 1) {
            double ov = shfl_xor_f64(best, m);
            int    ok = __shfl_xor(bestk, m, 64);
            if (ov < best || (ov == best && ok < bestk)) { best = ov; bestk = ok; }
        }
        if ((t & 63) == 0) { wbv[t >> 6] = best; wbk[t >> 6] = bestk; }
        __syncthreads();
        if (t == 0) {
            double bv = wbv[0]; int bb = wbk[0];
            for (int w = 1; w < 4; ++w)
                if (wbv[w] < bv || (wbv[w] == bv && wbk[w] < bb)) { bv = wbv[w]; bb = wbk[w]; }
            bks = bb;
        }
        __syncthreads();
        if (t < D) out[(size_t)row * D + t] = ET[(size_t)bks * D + t];
        __syncthreads();
    }
}

extern "C" void kernel_launch(void* const* d_in, const int* in_sizes, int n_in,
                              void* d_out, int out_size, void* d_ws, size_t ws_size,
                              hipStream_t stream) {
    const float* x = (const float*)d_in[0];
    const float* E = (const float*)d_in[1];
    float* out = (float*)d_out;
    int N = in_sizes[0] / D;   // 131072

    // ws: e_sq64 8K | e_sq32 4K | ET 256K | Bhi 128K | Blo 128K | count 16B | list 128K
    char* w = (char*)d_ws;
    double*         e_sq64 = (double*)w;          w += K * sizeof(double);
    float*          e_sq32 = (float*)w;           w += K * sizeof(float);
    float*          ET     = (float*)w;           w += (size_t)K * D * sizeof(float);
    unsigned short* Bhi    = (unsigned short*)w;  w += (size_t)K * D * sizeof(unsigned short);
    unsigned short* Blo    = (unsigned short*)w;  w += (size_t)K * D * sizeof(unsigned short);
    int*            count  = (int*)w;             w += 16;
    int*            list   = (int*)w;

    vq_prep<<<256, 256, 0, stream>>>(E, e_sq64, e_sq32, ET, Bhi, Blo, count);
    vq_screen<<<N / 64, 256, 0, stream>>>(x, (const short8*)Bhi, (const short8*)Blo,
                                          e_sq32, ET, out, count, list);
    vq_refine<<<1024, 256, 0, stream>>>(x, E, e_sq64, ET, out, count, list);
}